// Round 2
// baseline (62.701 us; speedup 1.0000x reference)
//
#include <hip/hip_runtime.h>
#include <hip/hip_bf16.h>

// kernel[i,j] = | prod_{k<16} cos((x[i,k]-y[j,k])/2) |   (f32 in, f32 out)
//
// r15: fully fused, register-only, single launch. Each wave owns one 32x32
// output tile; each lane computes its OWN row's and col's factor granules
// in registers (16 __sincosf + 64 mults + 32 packs per lane), so there is
// no LDS, no barrier, no ds_read, no staging store, and no second kernel.
// r14's lesson: the 32x-redundant staging was never the bottleneck (it's
// overlapped); the extra launch cost +2 us. r12's lesson: stores must be
// full-line (lane dim walks output columns).
//
// MFMA math identical to r13 (verified, absmax 0.0039): per wire pair
// cos(a)cos(b) = 1/2[cos(Rm-Cm)+cos(Rp-Cp)] -> 4-term separable dot; quad =
// 16-term dot; out = |Q0 Q1 Q2 Q3| via 4x mfma_f32_32x32x16_bf16 (K=16).
// A-operand lane l31 = row factors, B-operand lane l31 = col factors;
// D layout: col = lane&31, row = (reg&3)+8*(reg>>2)+4*(lane>>5) (m74/m101,
// validated numerically in r12/r13).
//
// Factor-vector layout per vector (64 bf16 = 4 quads x 16):
//   pos q*16 + kh*8 + e  =  fa[2*kh + e/4] * fb[e&3],  fa=f[2q], fb=f[2q+1]
// where f[pp] = scale * {cos(m), sin(m), cos(p), sin(p)},
//   m = (v[2pp]-v[2pp+1])/2, p = (v[2pp]+v[2pp+1])/2, scale = 0.5 (rows) / 1 (cols).

constexpr int D = 16;

typedef short  bf16x8 __attribute__((ext_vector_type(8)));
typedef float  f32x16 __attribute__((ext_vector_type(16)));

static __device__ inline unsigned int pk2(float a, float b) {
    __hip_bfloat16 ha = __float2bfloat16(a);
    __hip_bfloat16 hb = __float2bfloat16(b);
    unsigned short ua, ub;
    __builtin_memcpy(&ua, &ha, 2);
    __builtin_memcpy(&ub, &hb, 2);
    return (unsigned int)ua | ((unsigned int)ub << 16);
}

// Build one 8-bf16 MFMA granule: elements fa[2*kh + i]*fb[j], i<2, j<4.
// kh is a runtime (wave-uniform-per-half) value: select with ternaries so
// no runtime-indexed array goes to scratch (rule: dynamic idx -> localMem).
static __device__ inline bf16x8 mkfrag(const float* fa, const float* fb, int kh) {
    const float a0 = kh ? fa[2] : fa[0];
    const float a1 = kh ? fa[3] : fa[1];
    unsigned int w[4];
    w[0] = pk2(a0 * fb[0], a0 * fb[1]);
    w[1] = pk2(a0 * fb[2], a0 * fb[3]);
    w[2] = pk2(a1 * fb[0], a1 * fb[1]);
    w[3] = pk2(a1 * fb[2], a1 * fb[3]);
    bf16x8 r;
    __builtin_memcpy(&r, w, 16);
    return r;
}

// Compute the 4 granules (q=0..3) for one input vector of 16 f32.
static __device__ inline void mkside(const float* __restrict__ src, float scale,
                                     int kh, bf16x8 frag[4]) {
    float e[16];
    *(float4*)(e + 0)  = *(const float4*)(src + 0);
    *(float4*)(e + 4)  = *(const float4*)(src + 4);
    *(float4*)(e + 8)  = *(const float4*)(src + 8);
    *(float4*)(e + 12) = *(const float4*)(src + 12);

    float f[8][4];
#pragma unroll
    for (int pp = 0; pp < 8; ++pp) {
        const float a0 = e[2 * pp], a1 = e[2 * pp + 1];
        float sm, cm, sp, cp;
        __sincosf(0.5f * (a0 - a1), &sm, &cm);
        __sincosf(0.5f * (a0 + a1), &sp, &cp);
        f[pp][0] = scale * cm; f[pp][1] = scale * sm;
        f[pp][2] = scale * cp; f[pp][3] = scale * sp;
    }
#pragma unroll
    for (int q = 0; q < 4; ++q)
        frag[q] = mkfrag(f[2 * q], f[2 * q + 1], kh);
}

__global__ __launch_bounds__(256)
void qkern(const float* __restrict__ x, const float* __restrict__ y,
           float* __restrict__ out, int m) {
    const int wave = threadIdx.x >> 6;
    const int lane = threadIdx.x & 63;
    const int l31  = lane & 31;
    const int kh   = lane >> 5;                      // k-half within each quad
    const int rb   = blockIdx.x * 2 + (wave >> 1);   // 32-row block
    const int cb   = blockIdx.y * 2 + (wave & 1);    // 32-col block

    bf16x8 a[4], b[4];
    mkside(x + (size_t)(rb * 32 + l31) * D, 0.5f, kh, a);  // 0.25/quad -> 2^-8 total
    mkside(y + (size_t)(cb * 32 + l31) * D, 1.0f, kh, b);

    const f32x16 zc = {0.f};
    f32x16 q0 = __builtin_amdgcn_mfma_f32_32x32x16_bf16(a[0], b[0], zc, 0, 0, 0);
    f32x16 q1 = __builtin_amdgcn_mfma_f32_32x32x16_bf16(a[1], b[1], zc, 0, 0, 0);
    f32x16 q2 = __builtin_amdgcn_mfma_f32_32x32x16_bf16(a[2], b[2], zc, 0, 0, 0);
    f32x16 q3 = __builtin_amdgcn_mfma_f32_32x32x16_bf16(a[3], b[3], zc, 0, 0, 0);
    const f32x16 prod = (q0 * q1) * (q2 * q3);

    // D reg r -> row = 32*rb + (r&3) + 8*(r>>2) + 4*kh; col = 32*cb + l31.
    // Lanes walk contiguous cols -> each store inst covers 2 full 128 B lines.
    const int ocol = cb * 32 + l31;
    float* base = out + (size_t)(rb * 32 + 4 * kh) * m + ocol;
#pragma unroll
    for (int r = 0; r < 16; ++r) {
        const int row_off = (r & 3) + 8 * (r >> 2);
        __builtin_nontemporal_store(fabsf(prod[r]), base + (size_t)row_off * m);
    }
}

extern "C" void kernel_launch(void* const* d_in, const int* in_sizes, int n_in,
                              void* d_out, int out_size, void* d_ws, size_t ws_size,
                              hipStream_t stream) {
    const float* x = (const float*)d_in[0];
    const float* y = (const float*)d_in[1];
    float* out = (float*)d_out;
    const int n = in_sizes[0] / D;   // 2048
    const int m = in_sizes[1] / D;   // 2048

    dim3 grid(n / 64, m / 64);       // 32 x 32 blocks x 4 waves = one 32x32 tile/wave
    qkern<<<grid, 256, 0, stream>>>(x, y, out, m);
}

// Round 3
// 62.473 us; speedup vs baseline: 1.0036x; 1.0036x over previous
//
#include <hip/hip_runtime.h>
#include <hip/hip_bf16.h>

// kernel[i,j] = | prod_{k<16} cos((x[i,k]-y[j,k])/2) |   (f32 in, f32 out)
//
// r16 = r13 (best measured, 60.5 us) with plain stores instead of
// nontemporal: output (16.8 MB) fits L2/L3, so letting stores land dirty
// in cache moves the HBM writeback out of the kernel's critical path.
// r14 (split kernels) and r15 (register-only fused) both regressed —
// r13's staged structure is balanced: staging hides under occupancy,
// stores are full-line (lane dim walks output columns).
//
// MFMA formulation (verified r10-r13, absmax 0.0039): per wire pair
//   cos(a)cos(b) = 1/2[cos(Rm-Cm) + cos(Rp-Cp)]  -> 4-term separable dot;
// quad (pair x pair) = 16-term dot; out = |Q0 Q1 Q2 Q3| via 4x
// mfma_f32_32x32x16_bf16 (K=16 exact). A=row factors, B=col factors =>
// D's LANE dim = output column (m74/m101; validated numerically in r12).

constexpr int D = 16;
constexpr int RSTR = 72;   // LDS row stride in shorts (144 B, 16B-aligned)

typedef short  bf16x8 __attribute__((ext_vector_type(8)));
typedef float  f32x16 __attribute__((ext_vector_type(16)));

static __device__ inline unsigned int pk2(float a, float b) {
    __hip_bfloat16 ha = __float2bfloat16(a);
    __hip_bfloat16 hb = __float2bfloat16(b);
    unsigned short ua, ub;
    __builtin_memcpy(&ua, &ha, 2);
    __builtin_memcpy(&ub, &hb, 2);
    return (unsigned int)ua | ((unsigned int)ub << 16);
}

__global__ __launch_bounds__(256)
void qkern(const float* __restrict__ x, const float* __restrict__ y,
           float* __restrict__ out, int m) {
    __shared__ unsigned short Al[64 * RSTR];   // row terms: 64 rows x 64 bf16
    __shared__ unsigned short Bl[64 * RSTR];   // col terms: 64 cols x 64 bf16

    const int tid   = threadIdx.x;
    const int row0b = blockIdx.x * 64;
    const int col0b = blockIdx.y * 64;

    // ---- Stage: 128 units, 2 threads/unit. ----
    {
        const int u    = tid >> 1;
        const int half = tid & 1;
        const bool isrow = (u < 64);
        const float* src = isrow ? (x + (size_t)(row0b + u) * D)
                                 : (y + (size_t)(col0b + (u - 64)) * D);
        unsigned short* dst = (isrow ? Al + (size_t)u * RSTR
                                     : Bl + (size_t)(u - 64) * RSTR);
        const float scale = isrow ? 0.5f : 1.0f;

        float f[4][4];
#pragma unroll
        for (int pp = 0; pp < 4; ++pp) {
            const int p = half * 4 + pp;
            const float a0 = src[2 * p], a1 = src[2 * p + 1];
            float sm, cm, sp, cp;
            __sincosf(0.5f * (a0 - a1), &sm, &cm);
            __sincosf(0.5f * (a0 + a1), &sp, &cp);
            f[pp][0] = scale * cm; f[pp][1] = scale * sm;
            f[pp][2] = scale * cp; f[pp][3] = scale * sp;
        }
#pragma unroll
        for (int qq = 0; qq < 2; ++qq) {
            const int q = half * 2 + qq;
            const float* fa = f[2 * qq];
            const float* fb = f[2 * qq + 1];
            uint4 lo, hi;
            lo.x = pk2(fa[0] * fb[0], fa[0] * fb[1]);
            lo.y = pk2(fa[0] * fb[2], fa[0] * fb[3]);
            lo.z = pk2(fa[1] * fb[0], fa[1] * fb[1]);
            lo.w = pk2(fa[1] * fb[2], fa[1] * fb[3]);
            hi.x = pk2(fa[2] * fb[0], fa[2] * fb[1]);
            hi.y = pk2(fa[2] * fb[2], fa[2] * fb[3]);
            hi.z = pk2(fa[3] * fb[0], fa[3] * fb[1]);
            hi.w = pk2(fa[3] * fb[2], fa[3] * fb[3]);
            *(uint4*)(dst + q * 16)     = lo;
            *(uint4*)(dst + q * 16 + 8) = hi;
        }
    }
    __syncthreads();

    // ---- MFMA: wave = one 32x32 quadrant. A=rows, B=cols. ----
    const int wave = tid >> 6;
    const int lane = tid & 63;
    const int l31  = lane & 31;
    const int kh   = lane >> 5;          // k-half: 0 -> k0..7, 1 -> k8..15
    const int rw   = (wave >> 1) * 32;   // quadrant row base
    const int cw   = (wave & 1) * 32;    // quadrant col base

    const f32x16 zc = {0.f};

    f32x16 prod;
    {
        const bf16x8 a0 = *(const bf16x8*)(Al + (size_t)(rw + l31) * RSTR + 0 * 16 + kh * 8);
        const bf16x8 b0 = *(const bf16x8*)(Bl + (size_t)(cw + l31) * RSTR + 0 * 16 + kh * 8);
        prod = __builtin_amdgcn_mfma_f32_32x32x16_bf16(a0, b0, zc, 0, 0, 0);
    }
#pragma unroll
    for (int q = 1; q < 4; ++q) {
        const bf16x8 aq = *(const bf16x8*)(Al + (size_t)(rw + l31) * RSTR + q * 16 + kh * 8);
        const bf16x8 bq = *(const bf16x8*)(Bl + (size_t)(cw + l31) * RSTR + q * 16 + kh * 8);
        const f32x16 acc = __builtin_amdgcn_mfma_f32_32x32x16_bf16(aq, bq, zc, 0, 0, 0);
        prod *= acc;
    }

    // Epilogue: D reg r -> row = rw + (r&3) + 8*(r>>2) + 4*kh; col = cw+l31.
    // Lanes walk contiguous cols -> each store = 2 x 128 B full-line segments.
    // Plain (cached) stores: output fits L3; writeback drains off-path.
    const int ocol = col0b + cw + l31;
    float* base = out + (size_t)(row0b + rw + 4 * kh) * m + ocol;
#pragma unroll
    for (int r = 0; r < 16; ++r) {
        const int row_off = (r & 3) + 8 * (r >> 2);
        base[(size_t)row_off * m] = fabsf(prod[r]);
    }
}

extern "C" void kernel_launch(void* const* d_in, const int* in_sizes, int n_in,
                              void* d_out, int out_size, void* d_ws, size_t ws_size,
                              hipStream_t stream) {
    const float* x = (const float*)d_in[0];
    const float* y = (const float*)d_in[1];
    float* out = (float*)d_out;
    const int n = in_sizes[0] / D;   // 2048
    const int m = in_sizes[1] / D;   // 2048

    dim3 grid(n / 64, m / 64);       // 32 x 32 = 1024 blocks -> 4 blk/CU
    qkern<<<grid, 256, 0, stream>>>(x, y, out, m);
}

// Round 4
// 61.394 us; speedup vs baseline: 1.0213x; 1.0176x over previous
//
#include <hip/hip_runtime.h>
#include <hip/hip_bf16.h>

// kernel[i,j] = | prod_{k<16} cos((x[i,k]-y[j,k])/2) |   (f32 in, f32 out)
//
// r17 = r13 verbatim (best harness-verified: 60.51 us, round 0).
// Session bracket: r14 (split kernels, 62.5), r15 (register-only fused,
// 62.7), r16 (r13 minus NT stores, 62.5) — three structurally different
// kernels within 0.25 us of each other, all beaten only by r13. The NT
// hint is worth ~2 us (write-once output: stream it, don't dirty L2).
// Staging is hidden under occupancy; stores are full-line (lane dim walks
// output columns); qkern never appears in the top-5 dispatch table (the
// 268 MB harness re-poison fill at ~80% HBM dominates).
//
// MFMA formulation (verified r10-r13, absmax 0.0039): per wire pair
//   cos(a)cos(b) = 1/2[cos(Rm-Cm) + cos(Rp-Cp)]  -> 4-term separable dot;
// quad (pair x pair) = 16-term dot; out = |Q0 Q1 Q2 Q3| via 4x
// mfma_f32_32x32x16_bf16 (K=16 exact). A=row factors, B=col factors =>
// D's LANE dim = output column (m74/m101; validated numerically in r12).

constexpr int D = 16;
constexpr int RSTR = 72;   // LDS row stride in shorts (144 B, 16B-aligned)

typedef short  bf16x8 __attribute__((ext_vector_type(8)));
typedef float  f32x16 __attribute__((ext_vector_type(16)));

static __device__ inline unsigned int pk2(float a, float b) {
    __hip_bfloat16 ha = __float2bfloat16(a);
    __hip_bfloat16 hb = __float2bfloat16(b);
    unsigned short ua, ub;
    __builtin_memcpy(&ua, &ha, 2);
    __builtin_memcpy(&ub, &hb, 2);
    return (unsigned int)ua | ((unsigned int)ub << 16);
}

__global__ __launch_bounds__(256)
void qkern(const float* __restrict__ x, const float* __restrict__ y,
           float* __restrict__ out, int m) {
    __shared__ unsigned short Al[64 * RSTR];   // row terms: 64 rows x 64 bf16
    __shared__ unsigned short Bl[64 * RSTR];   // col terms: 64 cols x 64 bf16

    const int tid   = threadIdx.x;
    const int row0b = blockIdx.x * 64;
    const int col0b = blockIdx.y * 64;

    // ---- Stage: 128 units, 2 threads/unit. ----
    {
        const int u    = tid >> 1;
        const int half = tid & 1;
        const bool isrow = (u < 64);
        const float* src = isrow ? (x + (size_t)(row0b + u) * D)
                                 : (y + (size_t)(col0b + (u - 64)) * D);
        unsigned short* dst = (isrow ? Al + (size_t)u * RSTR
                                     : Bl + (size_t)(u - 64) * RSTR);
        const float scale = isrow ? 0.5f : 1.0f;

        float f[4][4];
#pragma unroll
        for (int pp = 0; pp < 4; ++pp) {
            const int p = half * 4 + pp;
            const float a0 = src[2 * p], a1 = src[2 * p + 1];
            float sm, cm, sp, cp;
            __sincosf(0.5f * (a0 - a1), &sm, &cm);
            __sincosf(0.5f * (a0 + a1), &sp, &cp);
            f[pp][0] = scale * cm; f[pp][1] = scale * sm;
            f[pp][2] = scale * cp; f[pp][3] = scale * sp;
        }
#pragma unroll
        for (int qq = 0; qq < 2; ++qq) {
            const int q = half * 2 + qq;
            const float* fa = f[2 * qq];
            const float* fb = f[2 * qq + 1];
            uint4 lo, hi;
            lo.x = pk2(fa[0] * fb[0], fa[0] * fb[1]);
            lo.y = pk2(fa[0] * fb[2], fa[0] * fb[3]);
            lo.z = pk2(fa[1] * fb[0], fa[1] * fb[1]);
            lo.w = pk2(fa[1] * fb[2], fa[1] * fb[3]);
            hi.x = pk2(fa[2] * fb[0], fa[2] * fb[1]);
            hi.y = pk2(fa[2] * fb[2], fa[2] * fb[3]);
            hi.z = pk2(fa[3] * fb[0], fa[3] * fb[1]);
            hi.w = pk2(fa[3] * fb[2], fa[3] * fb[3]);
            *(uint4*)(dst + q * 16)     = lo;
            *(uint4*)(dst + q * 16 + 8) = hi;
        }
    }
    __syncthreads();

    // ---- MFMA: wave = one 32x32 quadrant. A=rows, B=cols. ----
    const int wave = tid >> 6;
    const int lane = tid & 63;
    const int l31  = lane & 31;
    const int kh   = lane >> 5;          // k-half: 0 -> k0..7, 1 -> k8..15
    const int rw   = (wave >> 1) * 32;   // quadrant row base
    const int cw   = (wave & 1) * 32;    // quadrant col base

    const f32x16 zc = {0.f};

    f32x16 prod;
    {
        const bf16x8 a0 = *(const bf16x8*)(Al + (size_t)(rw + l31) * RSTR + 0 * 16 + kh * 8);
        const bf16x8 b0 = *(const bf16x8*)(Bl + (size_t)(cw + l31) * RSTR + 0 * 16 + kh * 8);
        prod = __builtin_amdgcn_mfma_f32_32x32x16_bf16(a0, b0, zc, 0, 0, 0);
    }
#pragma unroll
    for (int q = 1; q < 4; ++q) {
        const bf16x8 aq = *(const bf16x8*)(Al + (size_t)(rw + l31) * RSTR + q * 16 + kh * 8);
        const bf16x8 bq = *(const bf16x8*)(Bl + (size_t)(cw + l31) * RSTR + q * 16 + kh * 8);
        const f32x16 acc = __builtin_amdgcn_mfma_f32_32x32x16_bf16(aq, bq, zc, 0, 0, 0);
        prod *= acc;
    }

    // Epilogue: D reg r -> row = rw + (r&3) + 8*(r>>2) + 4*kh; col = cw+l31.
    // Lanes walk contiguous cols -> each store = 2 x 128 B full-line segments.
    const int ocol = col0b + cw + l31;
    float* base = out + (size_t)(row0b + rw + 4 * kh) * m + ocol;
#pragma unroll
    for (int r = 0; r < 16; ++r) {
        const int row_off = (r & 3) + 8 * (r >> 2);
        __builtin_nontemporal_store(fabsf(prod[r]), base + (size_t)row_off * m);
    }
}

extern "C" void kernel_launch(void* const* d_in, const int* in_sizes, int n_in,
                              void* d_out, int out_size, void* d_ws, size_t ws_size,
                              hipStream_t stream) {
    const float* x = (const float*)d_in[0];
    const float* y = (const float*)d_in[1];
    float* out = (float*)d_out;
    const int n = in_sizes[0] / D;   // 2048
    const int m = in_sizes[1] / D;   // 2048

    dim3 grid(n / 64, m / 64);       // 32 x 32 = 1024 blocks -> 4 blk/CU
    qkern<<<grid, 256, 0, stream>>>(x, y, out, m);
}